// Round 14
// baseline (47.427 us; speedup 1.0000x reference)
//
#include <hip/hip_runtime.h>
#include <math.h>

#define NN   96
#define NPOS (96*96)   // 9216
#define BB   32
#define KV   1024
#define KA   2048

// ws layout (float offsets)
#define EXTV_OFF  0
#define EXTA_OFF  (BB*NPOS)            // 294912
#define CPT_OFF   (3*BB*NPOS)          // 884736 (offsets kept stable)
#define AFV_OFF   (CPT_OFF + 6*NPOS)   // 940032
#define AFV_SLOTS ((KV/32)*2*64)       // 4096 16B-slots
#define AFA_OFF   (AFV_OFF + AFV_SLOTS*4)  // 956416
#define AFA_SLOTS ((KA/32)*2*64)       // 8192

typedef __bf16 bf16x8 __attribute__((ext_vector_type(8)));
typedef __bf16 bf16x4 __attribute__((ext_vector_type(4)));
typedef float  f32x4  __attribute__((ext_vector_type(4)));

// ---------------- nb (separable DoG) + vid/aud -> bf16 A-fragment pack ----------------
__global__ __launch_bounds__(256) void nbT_kernel(
    const float* __restrict__ na_v, const float* __restrict__ na_a,
    const float* __restrict__ na_m, const float* __restrict__ video,
    const float* __restrict__ audio, float* __restrict__ ws)
{
    __shared__ float G[96][100];
    __shared__ float act_s[96][100];
    __shared__ float T1t[24][100];

    if (blockIdx.x >= 24) {
        // A-fragment pack: A[16x32] lane layout row=l&15, k=(l>>4)*8+j
        const int e = (blockIdx.x - 24) * 256 + threadIdx.x;   // 0..12287
        const float* src; bf16x8* dst; int K, el;
        if (e < AFV_SLOTS) { src = video; K = KV; dst = (bf16x8*)(ws + AFV_OFF); el = e; }
        else               { src = audio; K = KA; dst = (bf16x8*)(ws + AFA_OFF); el = e - AFV_SLOTS; }
        const int l  = el & 63;
        const int hb = (el >> 6) & 1;
        const int sg = el >> 7;
        const int b  = hb * 16 + (l & 15);
        const int k0 = sg * 32 + ((l >> 4) << 3);
        const float4 f0 = *(const float4*)&src[(size_t)b * K + k0];
        const float4 f1 = *(const float4*)&src[(size_t)b * K + k0 + 4];
        bf16x8 v;
        v[0] = (__bf16)f0.x; v[1] = (__bf16)f0.y; v[2] = (__bf16)f0.z; v[3] = (__bf16)f0.w;
        v[4] = (__bf16)f1.x; v[5] = (__bf16)f1.y; v[6] = (__bf16)f1.z; v[7] = (__bf16)f1.w;
        dst[el] = v;
        return;
    }

    const int c  = blockIdx.x >> 2;
    const int js = (blockIdx.x & 3) * 24;
    float l, s;
    if      (c == 0) { l =  1.60f; s = 3.5f;  }
    else if (c == 1) { l = -1.23f; s = 6.3f;  }
    else if (c == 2) { l =  1.00f; s = 5.3f;  }
    else if (c == 3) { l = -0.80f; s = 11.8f; }
    else if (c == 4) { l =  3.80f; s = 3.5f;  }
    else             { l = -3.30f; s = 6.2f;  }
    const float s2 = s * s;
    const int f = c >> 1;
    const float* act = (f == 0) ? na_v : (f == 1) ? na_a : na_m;
    const int tid = threadIdx.x;
    float* cpt = ws + CPT_OFF;

    for (int idx = tid; idx < 9216; idx += 256) {
        int j = idx / 96, k = idx - j * 96;
        int d = abs(j - k); d = min(d, 96 - d);
        G[j][k]     = __expf(-0.5f * (float)(d * d) * s2);
        act_s[j][k] = act[idx];
    }
    __syncthreads();

    const int hg3 = (tid >> 3) * 3;
    const int jl3 = (tid & 7) * 3;

    float t1[3][3] = {};
    for (int k0 = 0; k0 < 96; k0 += 4) {
        float4 av[3], gv[3];
        #pragma unroll
        for (int r = 0; r < 3; r++) {
            av[r] = *(const float4*)&act_s[hg3 + r][k0];
            gv[r] = *(const float4*)&G[js + jl3 + r][k0];
        }
        #pragma unroll
        for (int hh = 0; hh < 3; hh++)
            #pragma unroll
            for (int jj = 0; jj < 3; jj++)
                t1[hh][jj] += av[hh].x * gv[jj].x + av[hh].y * gv[jj].y
                            + av[hh].z * gv[jj].z + av[hh].w * gv[jj].w;
    }
    #pragma unroll
    for (int hh = 0; hh < 3; hh++)
        #pragma unroll
        for (int jj = 0; jj < 3; jj++)
            T1t[jl3 + jj][hg3 + hh] = t1[hh][jj];
    __syncthreads();

    float o[3][3] = {};
    for (int h0 = 0; h0 < 96; h0 += 4) {
        float4 gv[3], tv[3];
        #pragma unroll
        for (int r = 0; r < 3; r++) {
            gv[r] = *(const float4*)&G[hg3 + r][h0];
            tv[r] = *(const float4*)&T1t[jl3 + r][h0];
        }
        #pragma unroll
        for (int ii = 0; ii < 3; ii++)
            #pragma unroll
            for (int jj = 0; jj < 3; jj++)
                o[ii][jj] += gv[ii].x * tv[jj].x + gv[ii].y * tv[jj].y
                           + gv[ii].z * tv[jj].z + gv[ii].w * tv[jj].w;
    }
    #pragma unroll
    for (int ii = 0; ii < 3; ii++)
        #pragma unroll
        for (int jj = 0; jj < 3; jj++)
            cpt[c * NPOS + (hg3 + ii) * 96 + (js + jl3 + jj)] = l * o[ii][jj];
}

// ---------------- ext GEMM: 32-pos full-K blocks (halves af traffic) ----------------
// Block = 32 pos x full K, 256 thr / 4 waves = (batch-half x pos-half) 16x16
// MFMA tiles, acc in-register across all k-steps (no split-K). Per 256-k step:
// dense stage (each wave-load = 1KB contiguous, r11's proven pattern) into
// double-buffered [32][528B] LDS (pad-528 -> compute ds_read_b128 exactly
// conflict-free; stage write 2-way = free). rf loads for s+1 issued BEFORE
// COMP(s) (T14 issue-early/write-late); af prefetched after COMP; one
// __syncthreads per step. Inbound traffic: rf 108 MB + af 55 MB (was 110).
#define LROW 528
#define BUFSZ (32*LROW)   // 16896
__global__ __launch_bounds__(256, 4) void ext_mfma(
    const float* __restrict__ rf_v, const float* __restrict__ rf_a,
    float* __restrict__ ws)
{
    __shared__ char lds[2 * BUFSZ];   // 33792 B -> 4 blocks/CU
    const int tid = threadIdx.x;
    const int bid = blockIdx.x;
    const int l = tid & 63, w = tid >> 6;

    const float* rf; const bf16x8* af; float* ext; int K, NS, pt;
    if (bid < 288) {                    // audio first (2x work)
        pt = bid; rf = rf_a; K = KA; NS = 8;
        af = (const bf16x8*)(ws + AFA_OFF); ext = ws + EXTA_OFF;
    } else {
        pt = bid - 288; rf = rf_v; K = KV; NS = 4;
        af = (const bf16x8*)(ws + AFV_OFF); ext = ws + EXTV_OFF;
    }
    const int p0 = pt * 32;

    // stage: thread covers rows w+4u (u=0..7) at float-col l*4 (1KB dense/instr)
    const float* src = rf + (size_t)(p0 + w) * K + l * 4;
    // compute lanes: wave = (bh, ph)
    const int bh = w & 1, ph = w >> 1;
    const int row   = ph * 16 + (l & 15);
    const int rboff = row * LROW + ((l >> 4) << 4);
    const bf16x8* ap = af + (bh << 6) + l;

    float4 fa[8];
    bf16x8 av0, av1, av2, av3, av4, av5, av6, av7;
    f32x4 acc = {0.f, 0.f, 0.f, 0.f};

#define LOADS(S) do {                                                      \
        _Pragma("unroll")                                                  \
        for (int u = 0; u < 8; ++u)                                        \
            fa[u] = *(const float4*)(src + (size_t)(4 * u) * K + (S) * 256); \
    } while (0)

#define WRITE(S) do {                                                      \
        char* bw = lds + ((S) & 1) * BUFSZ + l * 8;                        \
        _Pragma("unroll")                                                  \
        for (int u = 0; u < 8; ++u) {                                      \
            bf16x4 v;                                                      \
            v[0] = (__bf16)fa[u].x; v[1] = (__bf16)fa[u].y;                \
            v[2] = (__bf16)fa[u].z; v[3] = (__bf16)fa[u].w;                \
            *(bf16x4*)(bw + (w + 4 * u) * LROW) = v;                       \
        }                                                                  \
    } while (0)

#define AFLOAD(S) do {                                                     \
        const bf16x8* a_ = ap + (size_t)(S) * 8 * 128;                     \
        av0 = a_[0 * 128]; av1 = a_[1 * 128];                              \
        av2 = a_[2 * 128]; av3 = a_[3 * 128];                              \
        av4 = a_[4 * 128]; av5 = a_[5 * 128];                              \
        av6 = a_[6 * 128]; av7 = a_[7 * 128];                              \
    } while (0)

#define COMP(S) do {                                                           \
        const char* br = lds + ((S) & 1) * BUFSZ + rboff;                      \
        bf16x8 b;                                                              \
        b = *(const bf16x8*)(br + 0 * 64);                                     \
        acc = __builtin_amdgcn_mfma_f32_16x16x32_bf16(av0, b, acc, 0, 0, 0);   \
        b = *(const bf16x8*)(br + 1 * 64);                                     \
        acc = __builtin_amdgcn_mfma_f32_16x16x32_bf16(av1, b, acc, 0, 0, 0);   \
        b = *(const bf16x8*)(br + 2 * 64);                                     \
        acc = __builtin_amdgcn_mfma_f32_16x16x32_bf16(av2, b, acc, 0, 0, 0);   \
        b = *(const bf16x8*)(br + 3 * 64);                                     \
        acc = __builtin_amdgcn_mfma_f32_16x16x32_bf16(av3, b, acc, 0, 0, 0);   \
        b = *(const bf16x8*)(br + 4 * 64);                                     \
        acc = __builtin_amdgcn_mfma_f32_16x16x32_bf16(av4, b, acc, 0, 0, 0);   \
        b = *(const bf16x8*)(br + 5 * 64);                                     \
        acc = __builtin_amdgcn_mfma_f32_16x16x32_bf16(av5, b, acc, 0, 0, 0);   \
        b = *(const bf16x8*)(br + 6 * 64);                                     \
        acc = __builtin_amdgcn_mfma_f32_16x16x32_bf16(av6, b, acc, 0, 0, 0);   \
        b = *(const bf16x8*)(br + 7 * 64);                                     \
        acc = __builtin_amdgcn_mfma_f32_16x16x32_bf16(av7, b, acc, 0, 0, 0);   \
    } while (0)

    LOADS(0); AFLOAD(0); WRITE(0);
    __syncthreads();
    for (int s = 0; s < NS; ++s) {
        const int nxt = s + 1;
        if (nxt < NS) LOADS(nxt);       // rf stream in flight through COMP
        COMP(s);
        if (nxt < NS) { AFLOAD(nxt); WRITE(nxt); }
        __syncthreads();
    }

#undef LOADS
#undef WRITE
#undef AFLOAD
#undef COMP

    // C/D: col(pos) = l&15, row(batch) = (l>>4)*4 + reg
    const int pcol = p0 + ph * 16 + (l & 15);
    const int br0  = bh * 16 + ((l >> 4) << 2);
    #pragma unroll
    for (int r = 0; r < 4; ++r)
        ext[(size_t)(br0 + r) * NPOS + pcol] = acc[r];
}

// ---------------- combine: ext + cpt + sigmoid dynamics ----------------
__global__ __launch_bounds__(256) void combine_kernel(
    const float* __restrict__ na_v, const float* __restrict__ na_a,
    const float* __restrict__ na_m, const float* __restrict__ ws,
    float* __restrict__ out)
{
    const int npq = NPOS >> 2;
    const int t = blockIdx.x * 256 + threadIdx.x;
    if (t >= BB * npq) return;
    const int b  = t / npq;
    const int p0 = (t - b * npq) << 2;

    float4 ev = *(const float4*)&ws[EXTV_OFF + (size_t)b * NPOS + p0];
    float4 ea = *(const float4*)&ws[EXTA_OFF + (size_t)b * NPOS + p0];
    const float* cpt = ws + CPT_OFF;
    float4 q0 = *(const float4*)&cpt[0 * NPOS + p0];
    float4 q1 = *(const float4*)&cpt[1 * NPOS + p0];
    float4 q2 = *(const float4*)&cpt[2 * NPOS + p0];
    float4 q3 = *(const float4*)&cpt[3 * NPOS + p0];
    float4 q4 = *(const float4*)&cpt[4 * NPOS + p0];
    float4 q5 = *(const float4*)&cpt[5 * NPOS + p0];
    float4 nv = *(const float4*)&na_v[p0];
    float4 na = *(const float4*)&na_a[p0];
    float4 nm = *(const float4*)&na_m[p0];

    float evs[4] = {ev.x, ev.y, ev.z, ev.w};
    float eas[4] = {ea.x, ea.y, ea.z, ea.w};
    float nbv[4] = {q0.x + q1.x, q0.y + q1.y, q0.z + q1.z, q0.w + q1.w};
    float nba[4] = {q2.x + q3.x, q2.y + q3.y, q2.z + q3.z, q2.w + q3.w};
    float nbm[4] = {q4.x + q5.x, q4.y + q5.y, q4.z + q5.z, q4.w + q5.w};
    float nvs[4] = {nv.x, nv.y, nv.z, nv.w};
    float nas[4] = {na.x, na.y, na.z, na.w};
    float nms[4] = {nm.x, nm.y, nm.z, nm.w};

    float4 o;
    float* os = (float*)&o;
    #pragma unroll
    for (int u = 0; u < 4; u++) {
        const float xv = (evs[u] + nbv[u] - 3.0f + nms[u]) * 0.3f;
        const float nav_new = nvs[u] * (2.f / 3.f) + (1.f / 3.f) / (1.f + __expf(-xv));
        const float xa = (eas[u] + nba[u] - 3.0f + nms[u]) * 0.3f;
        const float naa_new = nas[u] * (2.f / 3.f) + (1.f / 3.f) / (1.f + __expf(-xa));
        const float xm = (7.0f * nav_new + 3.0f * naa_new + nbm[u] - 3.0f) * 0.3f;
        os[u] = nms[u] * (2.f / 3.f) + (1.f / 3.f) / (1.f + __expf(-xm));
    }
    *(float4*)&out[(size_t)b * NPOS + p0] = o;
}

extern "C" void kernel_launch(void* const* d_in, const int* in_sizes, int n_in,
                              void* d_out, int out_size, void* d_ws, size_t ws_size,
                              hipStream_t stream) {
    const float* video = (const float*)d_in[0];
    const float* audio = (const float*)d_in[1];
    const float* rf_v  = (const float*)d_in[2];
    const float* rf_a  = (const float*)d_in[3];
    const float* na_v  = (const float*)d_in[4];
    const float* na_a  = (const float*)d_in[5];
    const float* na_m  = (const float*)d_in[6];
    float* ws  = (float*)d_ws;
    float* out = (float*)d_out;

    nbT_kernel<<<72, 256, 0, stream>>>(na_v, na_a, na_m, video, audio, ws);
    ext_mfma<<<576, 256, 0, stream>>>(rf_v, rf_a, ws);
    combine_kernel<<<(BB * NPOS / 4 + 255) / 256, 256, 0, stream>>>(
        na_v, na_a, na_m, ws, out);
}

// Round 15
// 38.020 us; speedup vs baseline: 1.2474x; 1.2474x over previous
//
#include <hip/hip_runtime.h>
#include <math.h>

#define NN   96
#define NPOS (96*96)   // 9216
#define BB   32
#define KV   1024
#define KA   2048

// ws layout (float offsets)
#define EXTV_OFF  0
#define EXTA0_OFF (BB*NPOS)            // 294912
#define EXTA1_OFF (2*BB*NPOS)          // 589824
#define CPT_OFF   (3*BB*NPOS)          // 884736
#define AFV_OFF   (CPT_OFF + 6*NPOS)   // 940032
#define AFV_SLOTS ((KV/32)*2*64)       // 4096 16B-slots
#define AFA_OFF   (AFV_OFF + AFV_SLOTS*4)  // 956416
#define AFA_SLOTS ((KA/32)*2*64)       // 8192
// total ws ~ 4 MB

typedef __bf16 bf16x8 __attribute__((ext_vector_type(8)));
typedef __bf16 bf16x4 __attribute__((ext_vector_type(4)));
typedef float  f32x4  __attribute__((ext_vector_type(4)));

// ---------------- nb (separable DoG) + vid/aud -> bf16 A-fragment pack ----------------
__global__ __launch_bounds__(256) void nbT_kernel(
    const float* __restrict__ na_v, const float* __restrict__ na_a,
    const float* __restrict__ na_m, const float* __restrict__ video,
    const float* __restrict__ audio, float* __restrict__ ws)
{
    __shared__ float G[96][100];
    __shared__ float act_s[96][100];
    __shared__ float T1t[24][100];

    if (blockIdx.x >= 24) {
        // A-fragment pack: A[16x32] lane layout row=l&15, k=(l>>4)*8+j
        const int e = (blockIdx.x - 24) * 256 + threadIdx.x;   // 0..12287
        const float* src; bf16x8* dst; int K, el;
        if (e < AFV_SLOTS) { src = video; K = KV; dst = (bf16x8*)(ws + AFV_OFF); el = e; }
        else               { src = audio; K = KA; dst = (bf16x8*)(ws + AFA_OFF); el = e - AFV_SLOTS; }
        const int l  = el & 63;
        const int hb = (el >> 6) & 1;
        const int sg = el >> 7;
        const int b  = hb * 16 + (l & 15);
        const int k0 = sg * 32 + ((l >> 4) << 3);
        const float4 f0 = *(const float4*)&src[(size_t)b * K + k0];
        const float4 f1 = *(const float4*)&src[(size_t)b * K + k0 + 4];
        bf16x8 v;
        v[0] = (__bf16)f0.x; v[1] = (__bf16)f0.y; v[2] = (__bf16)f0.z; v[3] = (__bf16)f0.w;
        v[4] = (__bf16)f1.x; v[5] = (__bf16)f1.y; v[6] = (__bf16)f1.z; v[7] = (__bf16)f1.w;
        dst[el] = v;
        return;
    }

    const int c  = blockIdx.x >> 2;
    const int js = (blockIdx.x & 3) * 24;
    float l, s;
    if      (c == 0) { l =  1.60f; s = 3.5f;  }
    else if (c == 1) { l = -1.23f; s = 6.3f;  }
    else if (c == 2) { l =  1.00f; s = 5.3f;  }
    else if (c == 3) { l = -0.80f; s = 11.8f; }
    else if (c == 4) { l =  3.80f; s = 3.5f;  }
    else             { l = -3.30f; s = 6.2f;  }
    const float s2 = s * s;
    const int f = c >> 1;
    const float* act = (f == 0) ? na_v : (f == 1) ? na_a : na_m;
    const int tid = threadIdx.x;
    float* cpt = ws + CPT_OFF;

    for (int idx = tid; idx < 9216; idx += 256) {
        int j = idx / 96, k = idx - j * 96;
        int d = abs(j - k); d = min(d, 96 - d);
        G[j][k]     = __expf(-0.5f * (float)(d * d) * s2);
        act_s[j][k] = act[idx];
    }
    __syncthreads();

    const int hg3 = (tid >> 3) * 3;
    const int jl3 = (tid & 7) * 3;

    float t1[3][3] = {};
    for (int k0 = 0; k0 < 96; k0 += 4) {
        float4 av[3], gv[3];
        #pragma unroll
        for (int r = 0; r < 3; r++) {
            av[r] = *(const float4*)&act_s[hg3 + r][k0];
            gv[r] = *(const float4*)&G[js + jl3 + r][k0];
        }
        #pragma unroll
        for (int hh = 0; hh < 3; hh++)
            #pragma unroll
            for (int jj = 0; jj < 3; jj++)
                t1[hh][jj] += av[hh].x * gv[jj].x + av[hh].y * gv[jj].y
                            + av[hh].z * gv[jj].z + av[hh].w * gv[jj].w;
    }
    #pragma unroll
    for (int hh = 0; hh < 3; hh++)
        #pragma unroll
        for (int jj = 0; jj < 3; jj++)
            T1t[jl3 + jj][hg3 + hh] = t1[hh][jj];
    __syncthreads();

    float o[3][3] = {};
    for (int h0 = 0; h0 < 96; h0 += 4) {
        float4 gv[3], tv[3];
        #pragma unroll
        for (int r = 0; r < 3; r++) {
            gv[r] = *(const float4*)&G[hg3 + r][h0];
            tv[r] = *(const float4*)&T1t[jl3 + r][h0];
        }
        #pragma unroll
        for (int ii = 0; ii < 3; ii++)
            #pragma unroll
            for (int jj = 0; jj < 3; jj++)
                o[ii][jj] += gv[ii].x * tv[jj].x + gv[ii].y * tv[jj].y
                           + gv[ii].z * tv[jj].z + gv[ii].w * tv[jj].w;
    }
    #pragma unroll
    for (int ii = 0; ii < 3; ii++)
        #pragma unroll
        for (int jj = 0; jj < 3; jj++)
            cpt[c * NPOS + (hg3 + ii) * 96 + (js + jl3 + jj)] = l * o[ii][jj];
}

// ---------------- ext GEMM: dense-stream MFMA ----------------
// Block = 16 pos x 1024-k chunk, 256 threads. Staging: 16 loads/thread, each
// load instruction = 256 lanes x float4 = ONE CONTIGUOUS 4KB row-chunk (the
// 6.3 TB/s copy pattern). LDS rows padded to 2064 B (129 granules): reads AND
// writes conflict-free, no swizzle. Compute: wave = (batch-half, k-half),
// 16 MFMA steps; k-halves reduced via 2KB LDS. Latency hidden by block-level
// TLP (4 blocks/CU, 16 waves/CU in mixed stage/compute phases).
#define LDS_ROW 2064
__global__ __launch_bounds__(256, 4) void ext_mfma(
    const float* __restrict__ rf_v, const float* __restrict__ rf_a,
    float* __restrict__ ws)
{
    __shared__ char lds[16 * LDS_ROW + 2048];   // 35072 B
    const int tid = threadIdx.x;
    const int bid = blockIdx.x;

    const float* rf; const bf16x8* af; float* ext; int K, kb, pt;
    if (bid < 1152) {                   // audio: 576 pos-tiles x 2 k-chunks
        const int c = bid / 576; pt = bid - c * 576;
        rf = rf_a; K = KA; kb = c << 10;
        af  = (const bf16x8*)(ws + AFA_OFF);
        ext = ws + EXTA0_OFF + c * (BB * NPOS);
    } else {                            // video: 576 pos-tiles, one chunk
        pt = bid - 1152; rf = rf_v; K = KV; kb = 0;
        af  = (const bf16x8*)(ws + AFV_OFF);
        ext = ws + EXTV_OFF;
    }

    // ---- stage: rows 0..15, one dense 4KB load-instr per row, 8+8 pipelined
    {
        const float* src = rf + (size_t)(pt * 16) * K + kb + tid * 4;
        float4 fa[8];
        #pragma unroll
        for (int j = 0; j < 8; ++j) fa[j] = *(const float4*)(src + (size_t)j * K);
        #pragma unroll
        for (int j = 0; j < 8; ++j) {
            bf16x4 v;
            v[0] = (__bf16)fa[j].x; v[1] = (__bf16)fa[j].y;
            v[2] = (__bf16)fa[j].z; v[3] = (__bf16)fa[j].w;
            *(bf16x4*)(lds + j * LDS_ROW + tid * 8) = v;
        }
        #pragma unroll
        for (int j = 0; j < 8; ++j) fa[j] = *(const float4*)(src + (size_t)(j + 8) * K);
        #pragma unroll
        for (int j = 0; j < 8; ++j) {
            bf16x4 v;
            v[0] = (__bf16)fa[j].x; v[1] = (__bf16)fa[j].y;
            v[2] = (__bf16)fa[j].z; v[3] = (__bf16)fa[j].w;
            *(bf16x4*)(lds + (j + 8) * LDS_ROW + tid * 8) = v;
        }
    }
    __syncthreads();

    // ---- compute: wave = (bh, kh); 16 steps of 16x16x32 over 512 k
    const int l  = tid & 63, w = tid >> 6;
    const int bh = w & 1, kh = w >> 1;
    const bf16x8* ap = af + ((kb >> 5) + (kh << 4)) * 128 + (bh << 6) + l;
    const char*   bp = lds + (l & 15) * LDS_ROW + (kh << 10) + ((l >> 4) << 4);
    f32x4 acc = {0.f, 0.f, 0.f, 0.f};
    #pragma unroll
    for (int s = 0; s < 16; ++s) {
        bf16x8 a = ap[s * 128];                       // L2-hot A fragments
        bf16x8 b = *(const bf16x8*)(bp + s * 64);     // conflict-free ds_read
        acc = __builtin_amdgcn_mfma_f32_16x16x32_bf16(a, b, acc, 0, 0, 0);
    }

    // ---- k-half reduction: kh=1 writes, kh=0 adds and stores
    if (kh) *(f32x4*)(lds + 16 * LDS_ROW + (bh << 10) + l * 16) = acc;
    __syncthreads();
    if (!kh) {
        f32x4 o = *(const f32x4*)(lds + 16 * LDS_ROW + (bh << 10) + l * 16);
        acc += o;
        // C/D: col(pos) = l&15, row(batch) = (l>>4)*4 + reg
        const int pcol = pt * 16 + (l & 15);
        const int br0  = (bh << 4) + ((l >> 4) << 2);
        #pragma unroll
        for (int r = 0; r < 4; ++r)
            ext[(size_t)(br0 + r) * NPOS + pcol] = acc[r];
    }
}

// ---------------- combine: ext + cpt + sigmoid dynamics ----------------
__global__ __launch_bounds__(256) void combine_kernel(
    const float* __restrict__ na_v, const float* __restrict__ na_a,
    const float* __restrict__ na_m, const float* __restrict__ ws,
    float* __restrict__ out)
{
    const int npq = NPOS >> 2;
    const int t = blockIdx.x * 256 + threadIdx.x;
    if (t >= BB * npq) return;
    const int b  = t / npq;
    const int p0 = (t - b * npq) << 2;

    float4 ev  = *(const float4*)&ws[EXTV_OFF  + (size_t)b * NPOS + p0];
    float4 ea0 = *(const float4*)&ws[EXTA0_OFF + (size_t)b * NPOS + p0];
    float4 ea1 = *(const float4*)&ws[EXTA1_OFF + (size_t)b * NPOS + p0];
    float4 ea = {ea0.x + ea1.x, ea0.y + ea1.y, ea0.z + ea1.z, ea0.w + ea1.w};
    const float* cpt = ws + CPT_OFF;
    float4 q0 = *(const float4*)&cpt[0 * NPOS + p0];
    float4 q1 = *(const float4*)&cpt[1 * NPOS + p0];
    float4 q2 = *(const float4*)&cpt[2 * NPOS + p0];
    float4 q3 = *(const float4*)&cpt[3 * NPOS + p0];
    float4 q4 = *(const float4*)&cpt[4 * NPOS + p0];
    float4 q5 = *(const float4*)&cpt[5 * NPOS + p0];
    float4 nv = *(const float4*)&na_v[p0];
    float4 na = *(const float4*)&na_a[p0];
    float4 nm = *(const float4*)&na_m[p0];

    float evs[4] = {ev.x, ev.y, ev.z, ev.w};
    float eas[4] = {ea.x, ea.y, ea.z, ea.w};
    float nbv[4] = {q0.x + q1.x, q0.y + q1.y, q0.z + q1.z, q0.w + q1.w};
    float nba[4] = {q2.x + q3.x, q2.y + q3.y, q2.z + q3.z, q2.w + q3.w};
    float nbm[4] = {q4.x + q5.x, q4.y + q5.y, q4.z + q5.z, q4.w + q5.w};
    float nvs[4] = {nv.x, nv.y, nv.z, nv.w};
    float nas[4] = {na.x, na.y, na.z, na.w};
    float nms[4] = {nm.x, nm.y, nm.z, nm.w};

    float4 o;
    float* os = (float*)&o;
    #pragma unroll
    for (int u = 0; u < 4; u++) {
        const float xv = (evs[u] + nbv[u] - 3.0f + nms[u]) * 0.3f;
        const float nav_new = nvs[u] * (2.f / 3.f) + (1.f / 3.f) / (1.f + __expf(-xv));
        const float xa = (eas[u] + nba[u] - 3.0f + nms[u]) * 0.3f;
        const float naa_new = nas[u] * (2.f / 3.f) + (1.f / 3.f) / (1.f + __expf(-xa));
        const float xm = (7.0f * nav_new + 3.0f * naa_new + nbm[u] - 3.0f) * 0.3f;
        os[u] = nms[u] * (2.f / 3.f) + (1.f / 3.f) / (1.f + __expf(-xm));
    }
    *(float4*)&out[(size_t)b * NPOS + p0] = o;
}

extern "C" void kernel_launch(void* const* d_in, const int* in_sizes, int n_in,
                              void* d_out, int out_size, void* d_ws, size_t ws_size,
                              hipStream_t stream) {
    const float* video = (const float*)d_in[0];
    const float* audio = (const float*)d_in[1];
    const float* rf_v  = (const float*)d_in[2];
    const float* rf_a  = (const float*)d_in[3];
    const float* na_v  = (const float*)d_in[4];
    const float* na_a  = (const float*)d_in[5];
    const float* na_m  = (const float*)d_in[6];
    float* ws  = (float*)d_ws;
    float* out = (float*)d_out;

    nbT_kernel<<<72, 256, 0, stream>>>(na_v, na_a, na_m, video, audio, ws);
    ext_mfma<<<1728, 256, 0, stream>>>(rf_v, rf_a, ws);
    combine_kernel<<<(BB * NPOS / 4 + 255) / 256, 256, 0, stream>>>(
        na_v, na_a, na_m, ws, out);
}

// Round 16
// 37.833 us; speedup vs baseline: 1.2536x; 1.0049x over previous
//
#include <hip/hip_runtime.h>
#include <math.h>

#define NN   96
#define NPOS (96*96)   // 9216
#define BB   32
#define KV   1024
#define KA   2048

// ws layout (float offsets)
#define EXTV_OFF  0
#define EXTA0_OFF (BB*NPOS)            // 294912
#define EXTA1_OFF (2*BB*NPOS)          // 589824
#define CPT_OFF   (3*BB*NPOS)          // 884736
#define AFV_OFF   (CPT_OFF + 6*NPOS)   // 940032
#define AFV_SLOTS ((KV/32)*2*64)       // 4096 16B-slots
#define AFA_OFF   (AFV_OFF + AFV_SLOTS*4)  // 956416
#define AFA_SLOTS ((KA/32)*2*64)       // 8192
// total ws ~ 4 MB

typedef __bf16 bf16x8 __attribute__((ext_vector_type(8)));
typedef __bf16 bf16x4 __attribute__((ext_vector_type(4)));
typedef float  f32x4  __attribute__((ext_vector_type(4)));

// ---------------- nb (separable DoG) + vid/aud -> bf16 A-fragment pack ----------------
__global__ __launch_bounds__(256) void nbT_kernel(
    const float* __restrict__ na_v, const float* __restrict__ na_a,
    const float* __restrict__ na_m, const float* __restrict__ video,
    const float* __restrict__ audio, float* __restrict__ ws)
{
    __shared__ float G[96][100];
    __shared__ float act_s[96][100];
    __shared__ float T1t[24][100];

    if (blockIdx.x >= 24) {
        // A-fragment pack: A[16x32] lane layout row=l&15, k=(l>>4)*8+j
        const int e = (blockIdx.x - 24) * 256 + threadIdx.x;   // 0..12287
        const float* src; bf16x8* dst; int K, el;
        if (e < AFV_SLOTS) { src = video; K = KV; dst = (bf16x8*)(ws + AFV_OFF); el = e; }
        else               { src = audio; K = KA; dst = (bf16x8*)(ws + AFA_OFF); el = e - AFV_SLOTS; }
        const int l  = el & 63;
        const int hb = (el >> 6) & 1;
        const int sg = el >> 7;
        const int b  = hb * 16 + (l & 15);
        const int k0 = sg * 32 + ((l >> 4) << 3);
        const float4 f0 = *(const float4*)&src[(size_t)b * K + k0];
        const float4 f1 = *(const float4*)&src[(size_t)b * K + k0 + 4];
        bf16x8 v;
        v[0] = (__bf16)f0.x; v[1] = (__bf16)f0.y; v[2] = (__bf16)f0.z; v[3] = (__bf16)f0.w;
        v[4] = (__bf16)f1.x; v[5] = (__bf16)f1.y; v[6] = (__bf16)f1.z; v[7] = (__bf16)f1.w;
        dst[el] = v;
        return;
    }

    const int c  = blockIdx.x >> 2;
    const int js = (blockIdx.x & 3) * 24;
    float l, s;
    if      (c == 0) { l =  1.60f; s = 3.5f;  }
    else if (c == 1) { l = -1.23f; s = 6.3f;  }
    else if (c == 2) { l =  1.00f; s = 5.3f;  }
    else if (c == 3) { l = -0.80f; s = 11.8f; }
    else if (c == 4) { l =  3.80f; s = 3.5f;  }
    else             { l = -3.30f; s = 6.2f;  }
    const float s2 = s * s;
    const int f = c >> 1;
    const float* act = (f == 0) ? na_v : (f == 1) ? na_a : na_m;
    const int tid = threadIdx.x;
    float* cpt = ws + CPT_OFF;

    for (int idx = tid; idx < 9216; idx += 256) {
        int j = idx / 96, k = idx - j * 96;
        int d = abs(j - k); d = min(d, 96 - d);
        G[j][k]     = __expf(-0.5f * (float)(d * d) * s2);
        act_s[j][k] = act[idx];
    }
    __syncthreads();

    const int hg3 = (tid >> 3) * 3;
    const int jl3 = (tid & 7) * 3;

    float t1[3][3] = {};
    for (int k0 = 0; k0 < 96; k0 += 4) {
        float4 av[3], gv[3];
        #pragma unroll
        for (int r = 0; r < 3; r++) {
            av[r] = *(const float4*)&act_s[hg3 + r][k0];
            gv[r] = *(const float4*)&G[js + jl3 + r][k0];
        }
        #pragma unroll
        for (int hh = 0; hh < 3; hh++)
            #pragma unroll
            for (int jj = 0; jj < 3; jj++)
                t1[hh][jj] += av[hh].x * gv[jj].x + av[hh].y * gv[jj].y
                            + av[hh].z * gv[jj].z + av[hh].w * gv[jj].w;
    }
    #pragma unroll
    for (int hh = 0; hh < 3; hh++)
        #pragma unroll
        for (int jj = 0; jj < 3; jj++)
            T1t[jl3 + jj][hg3 + hh] = t1[hh][jj];
    __syncthreads();

    float o[3][3] = {};
    for (int h0 = 0; h0 < 96; h0 += 4) {
        float4 gv[3], tv[3];
        #pragma unroll
        for (int r = 0; r < 3; r++) {
            gv[r] = *(const float4*)&G[hg3 + r][h0];
            tv[r] = *(const float4*)&T1t[jl3 + r][h0];
        }
        #pragma unroll
        for (int ii = 0; ii < 3; ii++)
            #pragma unroll
            for (int jj = 0; jj < 3; jj++)
                o[ii][jj] += gv[ii].x * tv[jj].x + gv[ii].y * tv[jj].y
                           + gv[ii].z * tv[jj].z + gv[ii].w * tv[jj].w;
    }
    #pragma unroll
    for (int ii = 0; ii < 3; ii++)
        #pragma unroll
        for (int jj = 0; jj < 3; jj++)
            cpt[c * NPOS + (hg3 + ii) * 96 + (js + jl3 + jj)] = l * o[ii][jj];
}

// ---------------- ext GEMM: dense-stream MFMA ----------------
// Block = 16 pos x 1024-k chunk, 256 threads. Staging: 16 loads/thread, each
// load instruction = 256 lanes x float4 = ONE CONTIGUOUS 4KB row-chunk (the
// 6.3 TB/s copy pattern). LDS rows padded to 2064 B (129 granules): reads AND
// writes conflict-free, no swizzle. Compute: wave = (batch-half, k-half),
// 16 MFMA steps; k-halves reduced via 2KB LDS. Latency hidden by block-level
// TLP (4 blocks/CU, 16 waves/CU in mixed stage/compute phases).
#define LDS_ROW 2064
__global__ __launch_bounds__(256, 4) void ext_mfma(
    const float* __restrict__ rf_v, const float* __restrict__ rf_a,
    float* __restrict__ ws)
{
    __shared__ char lds[16 * LDS_ROW + 2048];   // 35072 B
    const int tid = threadIdx.x;
    const int bid = blockIdx.x;

    const float* rf; const bf16x8* af; float* ext; int K, kb, pt;
    if (bid < 1152) {                   // audio: 576 pos-tiles x 2 k-chunks
        const int c = bid / 576; pt = bid - c * 576;
        rf = rf_a; K = KA; kb = c << 10;
        af  = (const bf16x8*)(ws + AFA_OFF);
        ext = ws + EXTA0_OFF + c * (BB * NPOS);
    } else {                            // video: 576 pos-tiles, one chunk
        pt = bid - 1152; rf = rf_v; K = KV; kb = 0;
        af  = (const bf16x8*)(ws + AFV_OFF);
        ext = ws + EXTV_OFF;
    }

    // ---- stage: rows 0..15, one dense 4KB load-instr per row, 8+8 pipelined
    {
        const float* src = rf + (size_t)(pt * 16) * K + kb + tid * 4;
        float4 fa[8];
        #pragma unroll
        for (int j = 0; j < 8; ++j) fa[j] = *(const float4*)(src + (size_t)j * K);
        #pragma unroll
        for (int j = 0; j < 8; ++j) {
            bf16x4 v;
            v[0] = (__bf16)fa[j].x; v[1] = (__bf16)fa[j].y;
            v[2] = (__bf16)fa[j].z; v[3] = (__bf16)fa[j].w;
            *(bf16x4*)(lds + j * LDS_ROW + tid * 8) = v;
        }
        #pragma unroll
        for (int j = 0; j < 8; ++j) fa[j] = *(const float4*)(src + (size_t)(j + 8) * K);
        #pragma unroll
        for (int j = 0; j < 8; ++j) {
            bf16x4 v;
            v[0] = (__bf16)fa[j].x; v[1] = (__bf16)fa[j].y;
            v[2] = (__bf16)fa[j].z; v[3] = (__bf16)fa[j].w;
            *(bf16x4*)(lds + (j + 8) * LDS_ROW + tid * 8) = v;
        }
    }
    __syncthreads();

    // ---- compute: wave = (bh, kh); 16 steps of 16x16x32 over 512 k
    const int l  = tid & 63, w = tid >> 6;
    const int bh = w & 1, kh = w >> 1;
    const bf16x8* ap = af + ((kb >> 5) + (kh << 4)) * 128 + (bh << 6) + l;
    const char*   bp = lds + (l & 15) * LDS_ROW + (kh << 10) + ((l >> 4) << 4);
    f32x4 acc = {0.f, 0.f, 0.f, 0.f};
    #pragma unroll
    for (int s = 0; s < 16; ++s) {
        bf16x8 a = ap[s * 128];                       // L2-hot A fragments
        bf16x8 b = *(const bf16x8*)(bp + s * 64);     // conflict-free ds_read
        acc = __builtin_amdgcn_mfma_f32_16x16x32_bf16(a, b, acc, 0, 0, 0);
    }

    // ---- k-half reduction: kh=1 writes, kh=0 adds and stores
    if (kh) *(f32x4*)(lds + 16 * LDS_ROW + (bh << 10) + l * 16) = acc;
    __syncthreads();
    if (!kh) {
        f32x4 o = *(const f32x4*)(lds + 16 * LDS_ROW + (bh << 10) + l * 16);
        acc += o;
        // C/D: col(pos) = l&15, row(batch) = (l>>4)*4 + reg
        const int pcol = pt * 16 + (l & 15);
        const int br0  = (bh << 4) + ((l >> 4) << 2);
        #pragma unroll
        for (int r = 0; r < 4; ++r)
            ext[(size_t)(br0 + r) * NPOS + pcol] = acc[r];
    }
}

// ---------------- combine: ext + cpt + sigmoid dynamics ----------------
__global__ __launch_bounds__(256) void combine_kernel(
    const float* __restrict__ na_v, const float* __restrict__ na_a,
    const float* __restrict__ na_m, const float* __restrict__ ws,
    float* __restrict__ out)
{
    const int npq = NPOS >> 2;
    const int t = blockIdx.x * 256 + threadIdx.x;
    if (t >= BB * npq) return;
    const int b  = t / npq;
    const int p0 = (t - b * npq) << 2;

    float4 ev  = *(const float4*)&ws[EXTV_OFF  + (size_t)b * NPOS + p0];
    float4 ea0 = *(const float4*)&ws[EXTA0_OFF + (size_t)b * NPOS + p0];
    float4 ea1 = *(const float4*)&ws[EXTA1_OFF + (size_t)b * NPOS + p0];
    float4 ea = {ea0.x + ea1.x, ea0.y + ea1.y, ea0.z + ea1.z, ea0.w + ea1.w};
    const float* cpt = ws + CPT_OFF;
    float4 q0 = *(const float4*)&cpt[0 * NPOS + p0];
    float4 q1 = *(const float4*)&cpt[1 * NPOS + p0];
    float4 q2 = *(const float4*)&cpt[2 * NPOS + p0];
    float4 q3 = *(const float4*)&cpt[3 * NPOS + p0];
    float4 q4 = *(const float4*)&cpt[4 * NPOS + p0];
    float4 q5 = *(const float4*)&cpt[5 * NPOS + p0];
    float4 nv = *(const float4*)&na_v[p0];
    float4 na = *(const float4*)&na_a[p0];
    float4 nm = *(const float4*)&na_m[p0];

    float evs[4] = {ev.x, ev.y, ev.z, ev.w};
    float eas[4] = {ea.x, ea.y, ea.z, ea.w};
    float nbv[4] = {q0.x + q1.x, q0.y + q1.y, q0.z + q1.z, q0.w + q1.w};
    float nba[4] = {q2.x + q3.x, q2.y + q3.y, q2.z + q3.z, q2.w + q3.w};
    float nbm[4] = {q4.x + q5.x, q4.y + q5.y, q4.z + q5.z, q4.w + q5.w};
    float nvs[4] = {nv.x, nv.y, nv.z, nv.w};
    float nas[4] = {na.x, na.y, na.z, na.w};
    float nms[4] = {nm.x, nm.y, nm.z, nm.w};

    float4 o;
    float* os = (float*)&o;
    #pragma unroll
    for (int u = 0; u < 4; u++) {
        const float xv = (evs[u] + nbv[u] - 3.0f + nms[u]) * 0.3f;
        const float nav_new = nvs[u] * (2.f / 3.f) + (1.f / 3.f) / (1.f + __expf(-xv));
        const float xa = (eas[u] + nba[u] - 3.0f + nms[u]) * 0.3f;
        const float naa_new = nas[u] * (2.f / 3.f) + (1.f / 3.f) / (1.f + __expf(-xa));
        const float xm = (7.0f * nav_new + 3.0f * naa_new + nbm[u] - 3.0f) * 0.3f;
        os[u] = nms[u] * (2.f / 3.f) + (1.f / 3.f) / (1.f + __expf(-xm));
    }
    *(float4*)&out[(size_t)b * NPOS + p0] = o;
}

extern "C" void kernel_launch(void* const* d_in, const int* in_sizes, int n_in,
                              void* d_out, int out_size, void* d_ws, size_t ws_size,
                              hipStream_t stream) {
    const float* video = (const float*)d_in[0];
    const float* audio = (const float*)d_in[1];
    const float* rf_v  = (const float*)d_in[2];
    const float* rf_a  = (const float*)d_in[3];
    const float* na_v  = (const float*)d_in[4];
    const float* na_a  = (const float*)d_in[5];
    const float* na_m  = (const float*)d_in[6];
    float* ws  = (float*)d_ws;
    float* out = (float*)d_out;

    nbT_kernel<<<72, 256, 0, stream>>>(na_v, na_a, na_m, video, audio, ws);
    ext_mfma<<<1728, 256, 0, stream>>>(rf_v, rf_a, ws);
    combine_kernel<<<(BB * NPOS / 4 + 255) / 256, 256, 0, stream>>>(
        na_v, na_a, na_m, ws, out);
}